// Round 5
// baseline (386.574 us; speedup 1.0000x reference)
//
#include <hip/hip_runtime.h>
#include <math.h>

// ---------------------------------------------------------------------------
// 2-layer GCN. R5: fix gemm1 register spill.
// R4's gemm1 held float acc[64] per thread -> compiler allocated 56 VGPRs and
// spilled the accumulators to scratch (8192 scratch RMWs/thread, 93-113us).
// Now: 2 threads per row in DIFFERENT waves (wave-uniform f-half), acc[32]
// lives in VGPRs, W1 stays scalar-loaded (lane-invariant index).
// ---------------------------------------------------------------------------

#define CHUNK 8192        // edges per scatterA block
#define BSHIFT 9          // 512 nodes per bucket
#define BMASK 511
#define CAP 9216          // tmp slots per bucket (mean 8192, +11 sigma)

__device__ __forceinline__ unsigned f2b(float f) {  // fp32 -> bf16 bits (RNE)
  unsigned u = __float_as_uint(f);
  return (u + 0x7FFF + ((u >> 16) & 1)) >> 16;
}

__global__ void binit_kernel(int* __restrict__ gbcursor, int nbc) {
  int b = blockIdx.x * 256 + threadIdx.x;
  if (b < nbc) gbcursor[b] = b * CAP;
}

// Block multisplit: pass1 LDS bucket hist; one global atomic per (block,bucket)
// reserves a segment; pass2 places edges via LDS cursors. pack=(src<<9)|(dst&511).
__global__ __launch_bounds__(256) void scatterA_kernel(const int* __restrict__ src,
                                                       const int* __restrict__ dst,
                                                       int E, int nbc,
                                                       int* __restrict__ gbcursor,
                                                       int* __restrict__ tmp) {
  __shared__ int hist[256];
  __shared__ int segcur[256];
  int tid = threadIdx.x;
  int estart = blockIdx.x * CHUNK;
  int eend = min(E, estart + CHUNK);
  hist[tid] = 0;
  __syncthreads();
  for (int i = estart + tid; i < eend; i += 256)
    atomicAdd(&hist[dst[i] >> BSHIFT], 1);
  __syncthreads();
  if (tid < nbc) {
    int c = hist[tid];
    segcur[tid] = c ? atomicAdd(&gbcursor[tid], c) : 0;
  }
  __syncthreads();
  for (int i = estart + tid; i < eend; i += 256) {
    int d = dst[i];
    int b = d >> BSHIFT;
    int pos = atomicAdd(&segcur[b], 1);
    if (pos < (b + 1) * CAP)  // statistically impossible overflow guard
      tmp[pos] = (src[i] << BSHIFT) | (d & BMASK);
  }
}

// Per-node degree histogram from binned tmp (LDS atomics only).
__global__ __launch_bounds__(256) void hist2_kernel(const int* __restrict__ tmp,
                                                    const int* __restrict__ gbcursor,
                                                    int n, int* __restrict__ cnt) {
  __shared__ int nh[512];
  int b = blockIdx.x, tid = threadIdx.x;
  for (int v = tid; v < 512; v += 256) nh[v] = 0;
  __syncthreads();
  int base = b * CAP;
  int count = min(gbcursor[b] - base, CAP);
  for (int i = tid; i < count; i += 256) atomicAdd(&nh[tmp[base + i] & BMASK], 1);
  __syncthreads();
  int vb = b << BSHIFT;
  for (int v = tid; v < 512; v += 256) {
    int node = vb + v;
    if (node < n) cnt[node] = nh[v];
  }
}

__global__ void dinv_kernel(const int* __restrict__ cnt, float* __restrict__ dinv, int n) {
  int i = blockIdx.x * blockDim.x + threadIdx.x;
  if (i < n) dinv[i] = rsqrtf((float)(cnt[i] + 1));  // +1 self loop
}

__global__ void scan1_kernel(const int* __restrict__ cnt, int n,
                             int* __restrict__ partial, int* __restrict__ bsum) {
  __shared__ int sm[256];
  int tid = threadIdx.x;
  int i = blockIdx.x * 256 + tid;
  int v = (i < n) ? cnt[i] : 0;
  sm[tid] = v;
  __syncthreads();
  for (int off = 1; off < 256; off <<= 1) {
    int a = sm[tid];
    int b = (tid >= off) ? sm[tid - off] : 0;
    __syncthreads();
    sm[tid] = a + b;
    __syncthreads();
  }
  int inc = sm[tid];
  if (i < n) partial[i] = inc - v;
  if (tid == 255) bsum[blockIdx.x] = inc;
}

__global__ void scan2_kernel(const int* __restrict__ bsum, int nb, int* __restrict__ boffs) {
  __shared__ int sm[512];
  int tid = threadIdx.x;
  int v = (tid < nb) ? bsum[tid] : 0;
  sm[tid] = v;
  __syncthreads();
  for (int off = 1; off < 512; off <<= 1) {
    int a = sm[tid];
    int b = (tid >= off) ? sm[tid - off] : 0;
    __syncthreads();
    sm[tid] = a + b;
    __syncthreads();
  }
  boffs[tid] = sm[tid] - v;
}

__global__ void scan3_kernel(const int* __restrict__ boffs, int n, int E,
                             int* __restrict__ row_start) {
  int i = blockIdx.x * 256 + threadIdx.x;
  if (i < n) row_start[i] = row_start[i] + boffs[blockIdx.x];
  if (i == 0) row_start[n] = E;
}

// Final scatter: block per bucket, LDS per-node cursors, csr window ~64KB,
// single-CU-owned -> lines assemble in that XCD's L2.
__global__ __launch_bounds__(256) void scatterB_kernel(const int* __restrict__ tmp,
                                                       const int* __restrict__ gbcursor,
                                                       const int* __restrict__ row_start,
                                                       int n, int* __restrict__ csr) {
  __shared__ int lcur[512];
  int b = blockIdx.x, tid = threadIdx.x;
  int vb = b << BSHIFT;
  for (int v = tid; v < 512; v += 256) {
    int node = vb + v;
    lcur[v] = (node < n) ? row_start[node] : 0;
  }
  __syncthreads();
  int base = b * CAP;
  int count = min(gbcursor[b] - base, CAP);
  for (int i = tid; i < count; i += 256) {
    int val = tmp[base + i];
    int pos = atomicAdd(&lcur[val & BMASK], 1);
    csr[pos] = val >> BSHIFT;
  }
}

// h1s[row] = bf16x2-packed dinv[row] * (x[row] @ W1).
// Block = 128 rows x 4 waves. Wave w: rows (w>>1)*64 + lane, f-half (w&1)*32.
// f-half is wave-uniform -> W1 index lane-invariant -> scalar loads; acc[32]
// fits in VGPRs (no spill, unlike acc[64]).
__global__ __launch_bounds__(256) void gemm1_kernel(const float* __restrict__ x,
                                                    const float* __restrict__ W1,
                                                    const float* __restrict__ dinv,
                                                    unsigned* __restrict__ h1s, int n) {
  int tid = threadIdx.x;
  int lane = tid & 63;
  int fh = (tid >> 6) & 1;          // f-half: wave-uniform
  int rowgrp = tid >> 7;            // 0 or 1
  int row = blockIdx.x * 128 + rowgrp * 64 + lane;
  if (row >= n) return;
  const float4* x4 = (const float4*)(x + (size_t)row * 128);
  const float* W1h = W1 + fh * 32;  // wave-uniform base
  float acc[32];
#pragma unroll
  for (int f = 0; f < 32; ++f) acc[f] = 0.f;
#pragma unroll 4
  for (int k4 = 0; k4 < 32; ++k4) {
    float4 xv = x4[k4];
#pragma unroll
    for (int j = 0; j < 4; ++j) {
      float xs = (j == 0) ? xv.x : (j == 1) ? xv.y : (j == 2) ? xv.z : xv.w;
      const float* wrow = W1h + (size_t)(k4 * 4 + j) * 64;
#pragma unroll
      for (int f = 0; f < 32; ++f) acc[f] = fmaf(xs, wrow[f], acc[f]);
    }
  }
  float dv = dinv[row];
  unsigned u[16];
#pragma unroll
  for (int fp = 0; fp < 16; ++fp)
    u[fp] = (f2b(dv * acc[2 * fp + 1]) << 16) | f2b(dv * acc[2 * fp]);
  uint4* o4 = (uint4*)(h1s + (size_t)row * 32 + fh * 16);
#pragma unroll
  for (int q = 0; q < 4; ++q)
    o4[q] = make_uint4(u[4 * q], u[4 * q + 1], u[4 * q + 2], u[4 * q + 3]);
}

struct f2 { float x, y; };
__device__ __forceinline__ void addu(f2& a, unsigned u) {
  a.x += __uint_as_float(u << 16);
  a.y += __uint_as_float(u & 0xFFFF0000u);
}

// Wave-per-node. Lanes 0-31 process even edges, 32-63 odd edges; lane handles
// feature pair (2fp, 2fp+1) as one u32 load (row = 128B, fully coalesced per
// half-wave). 8 edges per main-loop iter -> 4 gathers in flight per lane.
__global__ __launch_bounds__(256) void agg1_kernel(const unsigned* __restrict__ h1s,
                                                   const float* __restrict__ dinv,
                                                   const int* __restrict__ row_start,
                                                   const int* __restrict__ csr,
                                                   const float* __restrict__ b1,
                                                   const float* __restrict__ W2,
                                                   float* __restrict__ t, int n) {
  __shared__ float W2s[64 * 17];
  __shared__ float a_s[4][64];
  for (int i = threadIdx.x; i < 1024; i += 256)
    W2s[(i >> 4) * 17 + (i & 15)] = W2[i];
  __syncthreads();

  int wave = threadIdx.x >> 6, lane = threadIdx.x & 63;
  int half = lane >> 5, fp = lane & 31;
  int v = blockIdx.x * 4 + wave;
  bool valid = (v < n);
  int vc = valid ? v : 0;

  float dv = dinv[vc];
  int e0 = row_start[vc], e1 = row_start[vc + 1];
  f2 a0 = {0.f, 0.f}, a1 = {0.f, 0.f}, a2 = {0.f, 0.f}, a3 = {0.f, 0.f};
  if (half == 0) addu(a0, h1s[(size_t)vc * 32 + fp]);  // self loop
  int i = e0;
  for (; i + 7 < e1; i += 8) {
    int s0 = csr[i], s1 = csr[i + 1], s2 = csr[i + 2], s3 = csr[i + 3];
    int s4 = csr[i + 4], s5 = csr[i + 5], s6 = csr[i + 6], s7 = csr[i + 7];
    unsigned u0 = h1s[(size_t)(half ? s1 : s0) * 32 + fp];
    unsigned u1 = h1s[(size_t)(half ? s3 : s2) * 32 + fp];
    unsigned u2 = h1s[(size_t)(half ? s5 : s4) * 32 + fp];
    unsigned u3 = h1s[(size_t)(half ? s7 : s6) * 32 + fp];
    addu(a0, u0); addu(a1, u1); addu(a2, u2); addu(a3, u3);
  }
  for (; i + 1 < e1; i += 2) {
    int s0 = csr[i], s1 = csr[i + 1];
    addu(a0, h1s[(size_t)(half ? s1 : s0) * 32 + fp]);
  }
  if (i < e1 && half == 0) addu(a0, h1s[(size_t)csr[i] * 32 + fp]);

  float ax = (a0.x + a1.x) + (a2.x + a3.x);
  float ay = (a0.y + a1.y) + (a2.y + a3.y);
  ax += __shfl_xor(ax, 32);  // combine even/odd halves
  ay += __shfl_xor(ay, 32);

  if (half == 0) {
    float z0 = fmaf(dv, ax, b1[2 * fp]);
    float z1 = fmaf(dv, ay, b1[2 * fp + 1]);
    a_s[wave][2 * fp] = fmaxf(z0, 0.2f * z0);
    a_s[wave][2 * fp + 1] = fmaxf(z1, 0.2f * z1);
  }
  __threadfence_block();

  int j = lane & 15, fb = (lane >> 4) << 4;
  float p = 0.f;
#pragma unroll
  for (int q = 0; q < 16; ++q) {
    int f = fb + q;
    p = fmaf(a_s[wave][f], W2s[f * 17 + j], p);
  }
  p += __shfl_xor(p, 16, 64);
  p += __shfl_xor(p, 32, 64);
  if (valid && lane < 16) t[(size_t)v * 16 + j] = dv * p;  // dinv folded for L2
}

// 16 lanes per node: acc = t[v] + sum t[csr[i]] (x4), z = dv*acc + b2, log_softmax.
__global__ __launch_bounds__(256) void agg2_kernel(const float* __restrict__ t,
                                                   const float* __restrict__ dinv,
                                                   const int* __restrict__ row_start,
                                                   const int* __restrict__ csr,
                                                   const float* __restrict__ b2,
                                                   float* __restrict__ out, int n) {
  int idx = blockIdx.x * 256 + threadIdx.x;
  int v = idx >> 4, j = idx & 15;
  if (v >= n) return;
  float dv = dinv[v];
  int e0 = row_start[v], e1 = row_start[v + 1];
  float acc0 = t[(size_t)v * 16 + j];  // self loop (already dinv-scaled)
  float acc1 = 0.f, acc2 = 0.f, acc3 = 0.f;
  int i = e0;
  for (; i + 3 < e1; i += 4) {
    int s0 = csr[i], s1 = csr[i + 1], s2 = csr[i + 2], s3 = csr[i + 3];
    float g0 = t[(size_t)s0 * 16 + j];
    float g1 = t[(size_t)s1 * 16 + j];
    float g2 = t[(size_t)s2 * 16 + j];
    float g3 = t[(size_t)s3 * 16 + j];
    acc0 += g0; acc1 += g1; acc2 += g2; acc3 += g3;
  }
  for (; i < e1; ++i) acc0 += t[(size_t)csr[i] * 16 + j];
  float z = fmaf(dv, (acc0 + acc1) + (acc2 + acc3), b2[j]);

  float m = z;
#pragma unroll
  for (int w = 1; w < 16; w <<= 1) m = fmaxf(m, __shfl_xor(m, w, 16));
  float p = expf(z - m);
  float ssum = p;
#pragma unroll
  for (int w = 1; w < 16; w <<= 1) ssum += __shfl_xor(ssum, w, 16);
  out[(size_t)v * 16 + j] = (z - m) - logf(ssum);
}

extern "C" void kernel_launch(void* const* d_in, const int* in_sizes, int n_in,
                              void* d_out, int out_size, void* d_ws, size_t ws_size,
                              hipStream_t stream) {
  const float* x = (const float*)d_in[0];
  const int* edge_index = (const int*)d_in[1];
  const float* W1 = (const float*)d_in[2];
  const float* b1 = (const float*)d_in[3];
  const float* W2 = (const float*)d_in[4];
  const float* b2 = (const float*)d_in[5];
  float* out = (float*)d_out;

  int N_ = in_sizes[0] / 128;
  int E_ = in_sizes[1] / 2;
  const int* src = edge_index;
  const int* dst = edge_index + E_;
  int NBc = (N_ + BMASK) >> BSHIFT;  // 196 buckets of 512 nodes (<= 256)

  char* ws = (char*)d_ws;
  size_t off = 0;
  auto take = [&](size_t bytes) {
    void* p = ws + off;
    off += (bytes + 255) & ~(size_t)255;
    return p;
  };
  unsigned* h1s = (unsigned*)take((size_t)N_ * 32 * 4);  // bf16x2 packed
  // t (N*16*4=6.4MB) aliases tmp (NBc*CAP*4=7.2MB): tmp dead before agg1.
  size_t t_bytes = (size_t)N_ * 16 * 4, tmp_bytes = (size_t)NBc * CAP * 4;
  void* t_union = take(t_bytes > tmp_bytes ? t_bytes : tmp_bytes);
  float* t = (float*)t_union;
  int* tmp = (int*)t_union;
  float* dinv = (float*)take((size_t)N_ * 4);
  int* cnt = (int*)take((size_t)N_ * 4);
  int* row_start = (int*)take(((size_t)N_ + 1) * 4);
  int* csr = (int*)take((size_t)E_ * 4);
  int* gbcursor = (int*)take((size_t)NBc * 4);
  int* bsum = (int*)take(512 * 4);
  int* boffs = (int*)take(512 * 4);
  (void)ws_size;

  int nbN = (N_ + 255) / 256;  // 391 (<= 512 for scan2)

  binit_kernel<<<(NBc + 255) / 256, 256, 0, stream>>>(gbcursor, NBc);
  scatterA_kernel<<<(E_ + CHUNK - 1) / CHUNK, 256, 0, stream>>>(src, dst, E_, NBc,
                                                                gbcursor, tmp);
  hist2_kernel<<<NBc, 256, 0, stream>>>(tmp, gbcursor, N_, cnt);
  dinv_kernel<<<nbN, 256, 0, stream>>>(cnt, dinv, N_);
  scan1_kernel<<<nbN, 256, 0, stream>>>(cnt, N_, row_start, bsum);
  scan2_kernel<<<1, 512, 0, stream>>>(bsum, nbN, boffs);
  scan3_kernel<<<nbN, 256, 0, stream>>>(boffs, N_, E_, row_start);
  scatterB_kernel<<<NBc, 256, 0, stream>>>(tmp, gbcursor, row_start, N_, csr);
  gemm1_kernel<<<(N_ + 127) / 128, 256, 0, stream>>>(x, W1, dinv, h1s, N_);
  agg1_kernel<<<(N_ + 3) / 4, 256, 0, stream>>>(h1s, dinv, row_start, csr, b1, W2, t, N_);
  agg2_kernel<<<(N_ * 16 + 255) / 256, 256, 0, stream>>>(t, dinv, row_start, csr, b2, out, N_);
}

// Round 6
// 291.089 us; speedup vs baseline: 1.3280x; 1.3280x over previous
//
#include <hip/hip_runtime.h>
#include <math.h>

// ---------------------------------------------------------------------------
// 2-layer GCN. R6: gemm1 = acc[32] split (no spill, from R5) + scalar W1 loads
// restored via readfirstlane (R5's regression: threadIdx-derived f-half made
// W1 addresses non-provably-uniform -> per-lane vector loads, SGPR 112->32).
// readfirstlane puts the W1 base pointer in an SGPR -> s_load again.
// ---------------------------------------------------------------------------

#define CHUNK 8192        // edges per scatterA block
#define BSHIFT 9          // 512 nodes per bucket
#define BMASK 511
#define CAP 9216          // tmp slots per bucket (mean 8192, +11 sigma)

__device__ __forceinline__ unsigned f2b(float f) {  // fp32 -> bf16 bits (RNE)
  unsigned u = __float_as_uint(f);
  return (u + 0x7FFF + ((u >> 16) & 1)) >> 16;
}

__global__ void binit_kernel(int* __restrict__ gbcursor, int nbc) {
  int b = blockIdx.x * 256 + threadIdx.x;
  if (b < nbc) gbcursor[b] = b * CAP;
}

// Block multisplit: pass1 LDS bucket hist; one global atomic per (block,bucket)
// reserves a segment; pass2 places edges via LDS cursors. pack=(src<<9)|(dst&511).
__global__ __launch_bounds__(256) void scatterA_kernel(const int* __restrict__ src,
                                                       const int* __restrict__ dst,
                                                       int E, int nbc,
                                                       int* __restrict__ gbcursor,
                                                       int* __restrict__ tmp) {
  __shared__ int hist[256];
  __shared__ int segcur[256];
  int tid = threadIdx.x;
  int estart = blockIdx.x * CHUNK;
  int eend = min(E, estart + CHUNK);
  hist[tid] = 0;
  __syncthreads();
  for (int i = estart + tid; i < eend; i += 256)
    atomicAdd(&hist[dst[i] >> BSHIFT], 1);
  __syncthreads();
  if (tid < nbc) {
    int c = hist[tid];
    segcur[tid] = c ? atomicAdd(&gbcursor[tid], c) : 0;
  }
  __syncthreads();
  for (int i = estart + tid; i < eend; i += 256) {
    int d = dst[i];
    int b = d >> BSHIFT;
    int pos = atomicAdd(&segcur[b], 1);
    if (pos < (b + 1) * CAP)  // statistically impossible overflow guard
      tmp[pos] = (src[i] << BSHIFT) | (d & BMASK);
  }
}

// Per-node degree histogram from binned tmp (LDS atomics only).
__global__ __launch_bounds__(256) void hist2_kernel(const int* __restrict__ tmp,
                                                    const int* __restrict__ gbcursor,
                                                    int n, int* __restrict__ cnt) {
  __shared__ int nh[512];
  int b = blockIdx.x, tid = threadIdx.x;
  for (int v = tid; v < 512; v += 256) nh[v] = 0;
  __syncthreads();
  int base = b * CAP;
  int count = min(gbcursor[b] - base, CAP);
  for (int i = tid; i < count; i += 256) atomicAdd(&nh[tmp[base + i] & BMASK], 1);
  __syncthreads();
  int vb = b << BSHIFT;
  for (int v = tid; v < 512; v += 256) {
    int node = vb + v;
    if (node < n) cnt[node] = nh[v];
  }
}

__global__ void dinv_kernel(const int* __restrict__ cnt, float* __restrict__ dinv, int n) {
  int i = blockIdx.x * blockDim.x + threadIdx.x;
  if (i < n) dinv[i] = rsqrtf((float)(cnt[i] + 1));  // +1 self loop
}

__global__ void scan1_kernel(const int* __restrict__ cnt, int n,
                             int* __restrict__ partial, int* __restrict__ bsum) {
  __shared__ int sm[256];
  int tid = threadIdx.x;
  int i = blockIdx.x * 256 + tid;
  int v = (i < n) ? cnt[i] : 0;
  sm[tid] = v;
  __syncthreads();
  for (int off = 1; off < 256; off <<= 1) {
    int a = sm[tid];
    int b = (tid >= off) ? sm[tid - off] : 0;
    __syncthreads();
    sm[tid] = a + b;
    __syncthreads();
  }
  int inc = sm[tid];
  if (i < n) partial[i] = inc - v;
  if (tid == 255) bsum[blockIdx.x] = inc;
}

__global__ void scan2_kernel(const int* __restrict__ bsum, int nb, int* __restrict__ boffs) {
  __shared__ int sm[512];
  int tid = threadIdx.x;
  int v = (tid < nb) ? bsum[tid] : 0;
  sm[tid] = v;
  __syncthreads();
  for (int off = 1; off < 512; off <<= 1) {
    int a = sm[tid];
    int b = (tid >= off) ? sm[tid - off] : 0;
    __syncthreads();
    sm[tid] = a + b;
    __syncthreads();
  }
  boffs[tid] = sm[tid] - v;
}

__global__ void scan3_kernel(const int* __restrict__ boffs, int n, int E,
                             int* __restrict__ row_start) {
  int i = blockIdx.x * 256 + threadIdx.x;
  if (i < n) row_start[i] = row_start[i] + boffs[blockIdx.x];
  if (i == 0) row_start[n] = E;
}

// Final scatter: block per bucket, LDS per-node cursors, csr window ~64KB,
// single-CU-owned -> lines assemble in that XCD's L2.
__global__ __launch_bounds__(256) void scatterB_kernel(const int* __restrict__ tmp,
                                                       const int* __restrict__ gbcursor,
                                                       const int* __restrict__ row_start,
                                                       int n, int* __restrict__ csr) {
  __shared__ int lcur[512];
  int b = blockIdx.x, tid = threadIdx.x;
  int vb = b << BSHIFT;
  for (int v = tid; v < 512; v += 256) {
    int node = vb + v;
    lcur[v] = (node < n) ? row_start[node] : 0;
  }
  __syncthreads();
  int base = b * CAP;
  int count = min(gbcursor[b] - base, CAP);
  for (int i = tid; i < count; i += 256) {
    int val = tmp[base + i];
    int pos = atomicAdd(&lcur[val & BMASK], 1);
    csr[pos] = val >> BSHIFT;
  }
}

// h1s[row] = bf16x2-packed dinv[row] * (x[row] @ W1).
// Block = 128 rows x 4 waves. Wave w: rows (w>>1)*64 + lane, f-half (w&1)*32.
// f-half goes through readfirstlane -> SGPR -> W1 loads stay scalar (s_load);
// acc[32] fits in VGPRs (no spill).
__global__ __launch_bounds__(256, 4) void gemm1_kernel(const float* __restrict__ x,
                                                       const float* __restrict__ W1,
                                                       const float* __restrict__ dinv,
                                                       unsigned* __restrict__ h1s, int n) {
  int tid = threadIdx.x;
  int lane = tid & 63;
  int fh = __builtin_amdgcn_readfirstlane((tid >> 6) & 1);  // wave-uniform, SGPR
  int rowgrp = tid >> 7;            // 0 or 1
  int row = blockIdx.x * 128 + rowgrp * 64 + lane;
  if (row >= n) return;
  const float4* x4 = (const float4*)(x + (size_t)row * 128);
  const float* W1h = W1 + fh * 32;  // SGPR base -> s_load path
  float acc[32];
#pragma unroll
  for (int f = 0; f < 32; ++f) acc[f] = 0.f;
#pragma unroll 4
  for (int k4 = 0; k4 < 32; ++k4) {
    float4 xv = x4[k4];
#pragma unroll
    for (int j = 0; j < 4; ++j) {
      float xs = (j == 0) ? xv.x : (j == 1) ? xv.y : (j == 2) ? xv.z : xv.w;
      const float* wrow = W1h + (size_t)(k4 * 4 + j) * 64;
#pragma unroll
      for (int f = 0; f < 32; ++f) acc[f] = fmaf(xs, wrow[f], acc[f]);
    }
  }
  float dv = dinv[row];
  unsigned u[16];
#pragma unroll
  for (int fp = 0; fp < 16; ++fp)
    u[fp] = (f2b(dv * acc[2 * fp + 1]) << 16) | f2b(dv * acc[2 * fp]);
  uint4* o4 = (uint4*)(h1s + (size_t)row * 32 + fh * 16);
#pragma unroll
  for (int q = 0; q < 4; ++q)
    o4[q] = make_uint4(u[4 * q], u[4 * q + 1], u[4 * q + 2], u[4 * q + 3]);
}

struct f2 { float x, y; };
__device__ __forceinline__ void addu(f2& a, unsigned u) {
  a.x += __uint_as_float(u << 16);
  a.y += __uint_as_float(u & 0xFFFF0000u);
}

// Wave-per-node. Lanes 0-31 process even edges, 32-63 odd edges; lane handles
// feature pair (2fp, 2fp+1) as one u32 load (row = 128B, fully coalesced per
// half-wave). 8 edges per main-loop iter -> 4 gathers in flight per lane.
__global__ __launch_bounds__(256) void agg1_kernel(const unsigned* __restrict__ h1s,
                                                   const float* __restrict__ dinv,
                                                   const int* __restrict__ row_start,
                                                   const int* __restrict__ csr,
                                                   const float* __restrict__ b1,
                                                   const float* __restrict__ W2,
                                                   float* __restrict__ t, int n) {
  __shared__ float W2s[64 * 17];
  __shared__ float a_s[4][64];
  for (int i = threadIdx.x; i < 1024; i += 256)
    W2s[(i >> 4) * 17 + (i & 15)] = W2[i];
  __syncthreads();

  int wave = threadIdx.x >> 6, lane = threadIdx.x & 63;
  int half = lane >> 5, fp = lane & 31;
  int v = blockIdx.x * 4 + wave;
  bool valid = (v < n);
  int vc = valid ? v : 0;

  float dv = dinv[vc];
  int e0 = row_start[vc], e1 = row_start[vc + 1];
  f2 a0 = {0.f, 0.f}, a1 = {0.f, 0.f}, a2 = {0.f, 0.f}, a3 = {0.f, 0.f};
  if (half == 0) addu(a0, h1s[(size_t)vc * 32 + fp]);  // self loop
  int i = e0;
  for (; i + 7 < e1; i += 8) {
    int s0 = csr[i], s1 = csr[i + 1], s2 = csr[i + 2], s3 = csr[i + 3];
    int s4 = csr[i + 4], s5 = csr[i + 5], s6 = csr[i + 6], s7 = csr[i + 7];
    unsigned u0 = h1s[(size_t)(half ? s1 : s0) * 32 + fp];
    unsigned u1 = h1s[(size_t)(half ? s3 : s2) * 32 + fp];
    unsigned u2 = h1s[(size_t)(half ? s5 : s4) * 32 + fp];
    unsigned u3 = h1s[(size_t)(half ? s7 : s6) * 32 + fp];
    addu(a0, u0); addu(a1, u1); addu(a2, u2); addu(a3, u3);
  }
  for (; i + 1 < e1; i += 2) {
    int s0 = csr[i], s1 = csr[i + 1];
    addu(a0, h1s[(size_t)(half ? s1 : s0) * 32 + fp]);
  }
  if (i < e1 && half == 0) addu(a0, h1s[(size_t)csr[i] * 32 + fp]);

  float ax = (a0.x + a1.x) + (a2.x + a3.x);
  float ay = (a0.y + a1.y) + (a2.y + a3.y);
  ax += __shfl_xor(ax, 32);  // combine even/odd halves
  ay += __shfl_xor(ay, 32);

  if (half == 0) {
    float z0 = fmaf(dv, ax, b1[2 * fp]);
    float z1 = fmaf(dv, ay, b1[2 * fp + 1]);
    a_s[wave][2 * fp] = fmaxf(z0, 0.2f * z0);
    a_s[wave][2 * fp + 1] = fmaxf(z1, 0.2f * z1);
  }
  __threadfence_block();

  int j = lane & 15, fb = (lane >> 4) << 4;
  float p = 0.f;
#pragma unroll
  for (int q = 0; q < 16; ++q) {
    int f = fb + q;
    p = fmaf(a_s[wave][f], W2s[f * 17 + j], p);
  }
  p += __shfl_xor(p, 16, 64);
  p += __shfl_xor(p, 32, 64);
  if (valid && lane < 16) t[(size_t)v * 16 + j] = dv * p;  // dinv folded for L2
}

// 16 lanes per node: acc = t[v] + sum t[csr[i]] (x4), z = dv*acc + b2, log_softmax.
__global__ __launch_bounds__(256) void agg2_kernel(const float* __restrict__ t,
                                                   const float* __restrict__ dinv,
                                                   const int* __restrict__ row_start,
                                                   const int* __restrict__ csr,
                                                   const float* __restrict__ b2,
                                                   float* __restrict__ out, int n) {
  int idx = blockIdx.x * 256 + threadIdx.x;
  int v = idx >> 4, j = idx & 15;
  if (v >= n) return;
  float dv = dinv[v];
  int e0 = row_start[v], e1 = row_start[v + 1];
  float acc0 = t[(size_t)v * 16 + j];  // self loop (already dinv-scaled)
  float acc1 = 0.f, acc2 = 0.f, acc3 = 0.f;
  int i = e0;
  for (; i + 3 < e1; i += 4) {
    int s0 = csr[i], s1 = csr[i + 1], s2 = csr[i + 2], s3 = csr[i + 3];
    float g0 = t[(size_t)s0 * 16 + j];
    float g1 = t[(size_t)s1 * 16 + j];
    float g2 = t[(size_t)s2 * 16 + j];
    float g3 = t[(size_t)s3 * 16 + j];
    acc0 += g0; acc1 += g1; acc2 += g2; acc3 += g3;
  }
  for (; i < e1; ++i) acc0 += t[(size_t)csr[i] * 16 + j];
  float z = fmaf(dv, (acc0 + acc1) + (acc2 + acc3), b2[j]);

  float m = z;
#pragma unroll
  for (int w = 1; w < 16; w <<= 1) m = fmaxf(m, __shfl_xor(m, w, 16));
  float p = expf(z - m);
  float ssum = p;
#pragma unroll
  for (int w = 1; w < 16; w <<= 1) ssum += __shfl_xor(ssum, w, 16);
  out[(size_t)v * 16 + j] = (z - m) - logf(ssum);
}

extern "C" void kernel_launch(void* const* d_in, const int* in_sizes, int n_in,
                              void* d_out, int out_size, void* d_ws, size_t ws_size,
                              hipStream_t stream) {
  const float* x = (const float*)d_in[0];
  const int* edge_index = (const int*)d_in[1];
  const float* W1 = (const float*)d_in[2];
  const float* b1 = (const float*)d_in[3];
  const float* W2 = (const float*)d_in[4];
  const float* b2 = (const float*)d_in[5];
  float* out = (float*)d_out;

  int N_ = in_sizes[0] / 128;
  int E_ = in_sizes[1] / 2;
  const int* src = edge_index;
  const int* dst = edge_index + E_;
  int NBc = (N_ + BMASK) >> BSHIFT;  // 196 buckets of 512 nodes (<= 256)

  char* ws = (char*)d_ws;
  size_t off = 0;
  auto take = [&](size_t bytes) {
    void* p = ws + off;
    off += (bytes + 255) & ~(size_t)255;
    return p;
  };
  unsigned* h1s = (unsigned*)take((size_t)N_ * 32 * 4);  // bf16x2 packed
  // t (N*16*4=6.4MB) aliases tmp (NBc*CAP*4=7.2MB): tmp dead before agg1.
  size_t t_bytes = (size_t)N_ * 16 * 4, tmp_bytes = (size_t)NBc * CAP * 4;
  void* t_union = take(t_bytes > tmp_bytes ? t_bytes : tmp_bytes);
  float* t = (float*)t_union;
  int* tmp = (int*)t_union;
  float* dinv = (float*)take((size_t)N_ * 4);
  int* cnt = (int*)take((size_t)N_ * 4);
  int* row_start = (int*)take(((size_t)N_ + 1) * 4);
  int* csr = (int*)take((size_t)E_ * 4);
  int* gbcursor = (int*)take((size_t)NBc * 4);
  int* bsum = (int*)take(512 * 4);
  int* boffs = (int*)take(512 * 4);
  (void)ws_size;

  int nbN = (N_ + 255) / 256;  // 391 (<= 512 for scan2)

  binit_kernel<<<(NBc + 255) / 256, 256, 0, stream>>>(gbcursor, NBc);
  scatterA_kernel<<<(E_ + CHUNK - 1) / CHUNK, 256, 0, stream>>>(src, dst, E_, NBc,
                                                                gbcursor, tmp);
  hist2_kernel<<<NBc, 256, 0, stream>>>(tmp, gbcursor, N_, cnt);
  dinv_kernel<<<nbN, 256, 0, stream>>>(cnt, dinv, N_);
  scan1_kernel<<<nbN, 256, 0, stream>>>(cnt, N_, row_start, bsum);
  scan2_kernel<<<1, 512, 0, stream>>>(bsum, nbN, boffs);
  scan3_kernel<<<nbN, 256, 0, stream>>>(boffs, N_, E_, row_start);
  scatterB_kernel<<<NBc, 256, 0, stream>>>(tmp, gbcursor, row_start, N_, csr);
  gemm1_kernel<<<(N_ + 127) / 128, 256, 0, stream>>>(x, W1, dinv, h1s, N_);
  agg1_kernel<<<(N_ + 3) / 4, 256, 0, stream>>>(h1s, dinv, row_start, csr, b1, W2, t, N_);
  agg2_kernel<<<(N_ * 16 + 255) / 256, 256, 0, stream>>>(t, dinv, row_start, csr, b2, out, N_);
}

// Round 7
// 272.588 us; speedup vs baseline: 1.4182x; 1.0679x over previous
//
#include <hip/hip_runtime.h>
#include <math.h>

// ---------------------------------------------------------------------------
// 2-layer GCN. R7: widen aggregation gathers.
//  - agg1: lane(e=lane>>3,c=lane&7) loads uint4 -> 8 edges per wave-load
//    (was 2), x2 unrolled (2KB in flight/wave). e-group xor-butterfly reduce.
//    Grid-stride amortizes W2s staging. Zero-row n makes tails branch-free.
//  - agg2: lane(e=sub>>2,c=sub&3) loads float4 -> 16 edges/wave-load; softmax
//    across c-lanes via xor 1/2.
// ---------------------------------------------------------------------------

#define CHUNK 8192        // edges per scatterA block
#define BSHIFT 9          // 512 nodes per bucket
#define BMASK 511
#define CAP 9216          // tmp slots per bucket (mean 8192, +11 sigma)

__device__ __forceinline__ unsigned f2b(float f) {  // fp32 -> bf16 bits (RNE)
  unsigned u = __float_as_uint(f);
  return (u + 0x7FFF + ((u >> 16) & 1)) >> 16;
}

// init bucket cursors + zero h1s row n (the "zero row" for masked gathers)
__global__ void binit_kernel(int* __restrict__ gbcursor, int nbc,
                             unsigned* __restrict__ h1s, int n) {
  int b = blockIdx.x * 256 + threadIdx.x;
  if (b < nbc) gbcursor[b] = b * CAP;
  if (blockIdx.x == 0 && threadIdx.x < 32) h1s[(size_t)n * 32 + threadIdx.x] = 0u;
}

// Block multisplit: pass1 LDS bucket hist; one global atomic per (block,bucket)
// reserves a segment; pass2 places edges via LDS cursors. pack=(src<<9)|(dst&511).
__global__ __launch_bounds__(256) void scatterA_kernel(const int* __restrict__ src,
                                                       const int* __restrict__ dst,
                                                       int E, int nbc,
                                                       int* __restrict__ gbcursor,
                                                       int* __restrict__ tmp) {
  __shared__ int hist[256];
  __shared__ int segcur[256];
  int tid = threadIdx.x;
  int estart = blockIdx.x * CHUNK;
  int eend = min(E, estart + CHUNK);
  hist[tid] = 0;
  __syncthreads();
  for (int i = estart + tid; i < eend; i += 256)
    atomicAdd(&hist[dst[i] >> BSHIFT], 1);
  __syncthreads();
  if (tid < nbc) {
    int c = hist[tid];
    segcur[tid] = c ? atomicAdd(&gbcursor[tid], c) : 0;
  }
  __syncthreads();
  for (int i = estart + tid; i < eend; i += 256) {
    int d = dst[i];
    int b = d >> BSHIFT;
    int pos = atomicAdd(&segcur[b], 1);
    if (pos < (b + 1) * CAP)  // statistically impossible overflow guard
      tmp[pos] = (src[i] << BSHIFT) | (d & BMASK);
  }
}

// Per-node degree histogram from binned tmp (LDS atomics only).
__global__ __launch_bounds__(256) void hist2_kernel(const int* __restrict__ tmp,
                                                    const int* __restrict__ gbcursor,
                                                    int n, int* __restrict__ cnt) {
  __shared__ int nh[512];
  int b = blockIdx.x, tid = threadIdx.x;
  for (int v = tid; v < 512; v += 256) nh[v] = 0;
  __syncthreads();
  int base = b * CAP;
  int count = min(gbcursor[b] - base, CAP);
  for (int i = tid; i < count; i += 256) atomicAdd(&nh[tmp[base + i] & BMASK], 1);
  __syncthreads();
  int vb = b << BSHIFT;
  for (int v = tid; v < 512; v += 256) {
    int node = vb + v;
    if (node < n) cnt[node] = nh[v];
  }
}

__global__ void dinv_kernel(const int* __restrict__ cnt, float* __restrict__ dinv, int n) {
  int i = blockIdx.x * blockDim.x + threadIdx.x;
  if (i < n) dinv[i] = rsqrtf((float)(cnt[i] + 1));  // +1 self loop
}

__global__ void scan1_kernel(const int* __restrict__ cnt, int n,
                             int* __restrict__ partial, int* __restrict__ bsum) {
  __shared__ int sm[256];
  int tid = threadIdx.x;
  int i = blockIdx.x * 256 + tid;
  int v = (i < n) ? cnt[i] : 0;
  sm[tid] = v;
  __syncthreads();
  for (int off = 1; off < 256; off <<= 1) {
    int a = sm[tid];
    int b = (tid >= off) ? sm[tid - off] : 0;
    __syncthreads();
    sm[tid] = a + b;
    __syncthreads();
  }
  int inc = sm[tid];
  if (i < n) partial[i] = inc - v;
  if (tid == 255) bsum[blockIdx.x] = inc;
}

__global__ void scan2_kernel(const int* __restrict__ bsum, int nb, int* __restrict__ boffs) {
  __shared__ int sm[512];
  int tid = threadIdx.x;
  int v = (tid < nb) ? bsum[tid] : 0;
  sm[tid] = v;
  __syncthreads();
  for (int off = 1; off < 512; off <<= 1) {
    int a = sm[tid];
    int b = (tid >= off) ? sm[tid - off] : 0;
    __syncthreads();
    sm[tid] = a + b;
    __syncthreads();
  }
  boffs[tid] = sm[tid] - v;
}

__global__ void scan3_kernel(const int* __restrict__ boffs, int n, int E,
                             int* __restrict__ row_start) {
  int i = blockIdx.x * 256 + threadIdx.x;
  if (i < n) row_start[i] = row_start[i] + boffs[blockIdx.x];
  if (i == 0) row_start[n] = E;
}

// Final scatter: block per bucket, LDS per-node cursors, csr window ~64KB,
// single-CU-owned -> lines assemble in that XCD's L2.
__global__ __launch_bounds__(256) void scatterB_kernel(const int* __restrict__ tmp,
                                                       const int* __restrict__ gbcursor,
                                                       const int* __restrict__ row_start,
                                                       int n, int* __restrict__ csr) {
  __shared__ int lcur[512];
  int b = blockIdx.x, tid = threadIdx.x;
  int vb = b << BSHIFT;
  for (int v = tid; v < 512; v += 256) {
    int node = vb + v;
    lcur[v] = (node < n) ? row_start[node] : 0;
  }
  __syncthreads();
  int base = b * CAP;
  int count = min(gbcursor[b] - base, CAP);
  for (int i = tid; i < count; i += 256) {
    int val = tmp[base + i];
    int pos = atomicAdd(&lcur[val & BMASK], 1);
    csr[pos] = val >> BSHIFT;
  }
}

// h1s[row] = bf16x2-packed dinv[row] * (x[row] @ W1).
// Block = 128 rows x 4 waves; f-half via readfirstlane -> scalar W1 loads;
// acc[32] in VGPRs (no spill). (R6-proven structure.)
__global__ __launch_bounds__(256, 4) void gemm1_kernel(const float* __restrict__ x,
                                                       const float* __restrict__ W1,
                                                       const float* __restrict__ dinv,
                                                       unsigned* __restrict__ h1s, int n) {
  int tid = threadIdx.x;
  int lane = tid & 63;
  int fh = __builtin_amdgcn_readfirstlane((tid >> 6) & 1);  // wave-uniform, SGPR
  int rowgrp = tid >> 7;            // 0 or 1
  int row = blockIdx.x * 128 + rowgrp * 64 + lane;
  if (row >= n) return;
  const float4* x4 = (const float4*)(x + (size_t)row * 128);
  const float* W1h = W1 + fh * 32;  // SGPR base -> s_load path
  float acc[32];
#pragma unroll
  for (int f = 0; f < 32; ++f) acc[f] = 0.f;
#pragma unroll 4
  for (int k4 = 0; k4 < 32; ++k4) {
    float4 xv = x4[k4];
#pragma unroll
    for (int j = 0; j < 4; ++j) {
      float xs = (j == 0) ? xv.x : (j == 1) ? xv.y : (j == 2) ? xv.z : xv.w;
      const float* wrow = W1h + (size_t)(k4 * 4 + j) * 64;
#pragma unroll
      for (int f = 0; f < 32; ++f) acc[f] = fmaf(xs, wrow[f], acc[f]);
    }
  }
  float dv = dinv[row];
  unsigned u[16];
#pragma unroll
  for (int fp = 0; fp < 16; ++fp)
    u[fp] = (f2b(dv * acc[2 * fp + 1]) << 16) | f2b(dv * acc[2 * fp]);
  uint4* o4 = (uint4*)(h1s + (size_t)row * 32 + fh * 16);
#pragma unroll
  for (int q = 0; q < 4; ++q)
    o4[q] = make_uint4(u[4 * q], u[4 * q + 1], u[4 * q + 2], u[4 * q + 3]);
}

struct f2 { float x, y; };
__device__ __forceinline__ void addu(f2& a, unsigned u) {
  a.x += __uint_as_float(u << 16);
  a.y += __uint_as_float(u & 0xFFFF0000u);
}

// Wave-per-node, uint4 gathers. lane: e=lane>>3 (edge slot), c=lane&7 (16B
// chunk = features 8c..8c+7). One wave-load = 8 edges' rows. Row n of h1s is
// zeros -> masked tail gathers are branch-free. Grid-stride over node groups.
__global__ __launch_bounds__(256) void agg1_kernel(const uint4* __restrict__ h1s4,
                                                   const float* __restrict__ dinv,
                                                   const int* __restrict__ row_start,
                                                   const int* __restrict__ csr,
                                                   const float* __restrict__ b1,
                                                   const float* __restrict__ W2,
                                                   float* __restrict__ t, int n) {
  __shared__ float W2s[64 * 17];
  __shared__ float b1s[64];
  __shared__ float a_s[4][64];
  for (int i = threadIdx.x; i < 1024; i += 256)
    W2s[(i >> 4) * 17 + (i & 15)] = W2[i];
  if (threadIdx.x < 64) b1s[threadIdx.x] = b1[threadIdx.x];
  // zero t row n for agg2's masked gathers (tmp alias is dead by now)
  if (blockIdx.x == 0 && threadIdx.x < 16) t[(size_t)n * 16 + threadIdx.x] = 0.f;
  __syncthreads();

  int wave = threadIdx.x >> 6, lane = threadIdx.x & 63;
  int e = lane >> 3, c = lane & 7;
  int j = lane & 15, fb = (lane >> 4) << 4;

  for (int vbase = blockIdx.x * 4; vbase < n; vbase += gridDim.x * 4) {
    int v = vbase + wave;
    bool valid = (v < n);           // wave-uniform
    int e0 = 0, e1 = 0;
    float dv = 0.f;
    if (valid) { e0 = row_start[v]; e1 = row_start[v + 1]; dv = dinv[v]; }

    f2 a0[4], a1[4];
#pragma unroll
    for (int k = 0; k < 4; ++k) { a0[k] = {0.f, 0.f}; a1[k] = {0.f, 0.f}; }
    {  // self loop (e==0 lanes pull row v; others pull zero row)
      int s = (valid && e == 0) ? v : n;
      uint4 g = h1s4[(size_t)s * 8 + c];
      addu(a0[0], g.x); addu(a0[1], g.y); addu(a0[2], g.z); addu(a0[3], g.w);
    }
    int i = e0;
    while (i + 8 < e1) {  // first gather fully valid, second masked
      int i1 = i + 8 + e;
      int s0 = csr[i + e];
      int s1v = csr[i1];
      int s1 = (i1 < e1) ? s1v : n;
      uint4 g0 = h1s4[(size_t)s0 * 8 + c];
      uint4 g1 = h1s4[(size_t)s1 * 8 + c];
      addu(a0[0], g0.x); addu(a0[1], g0.y); addu(a0[2], g0.z); addu(a0[3], g0.w);
      addu(a1[0], g1.x); addu(a1[1], g1.y); addu(a1[2], g1.z); addu(a1[3], g1.w);
      i += 16;
    }
    if (i < e1) {  // masked tail gather
      int i0 = i + e;
      int sv = csr[i0];
      int s = (i0 < e1) ? sv : n;
      uint4 g = h1s4[(size_t)s * 8 + c];
      addu(a0[0], g.x); addu(a0[1], g.y); addu(a0[2], g.z); addu(a0[3], g.w);
    }
#pragma unroll
    for (int k = 0; k < 4; ++k) { a0[k].x += a1[k].x; a0[k].y += a1[k].y; }
#pragma unroll
    for (int m = 8; m <= 32; m <<= 1) {
#pragma unroll
      for (int k = 0; k < 4; ++k) {
        a0[k].x += __shfl_xor(a0[k].x, m, 64);
        a0[k].y += __shfl_xor(a0[k].y, m, 64);
      }
    }
    if (lane < 8) {  // c == lane; features 8c..8c+7
#pragma unroll
      for (int k = 0; k < 4; ++k) {
        float z0 = fmaf(dv, a0[k].x, b1s[8 * lane + 2 * k]);
        float z1 = fmaf(dv, a0[k].y, b1s[8 * lane + 2 * k + 1]);
        a_s[wave][8 * lane + 2 * k] = fmaxf(z0, 0.2f * z0);
        a_s[wave][8 * lane + 2 * k + 1] = fmaxf(z1, 0.2f * z1);
      }
    }
    __threadfence_block();
    float p = 0.f;
#pragma unroll
    for (int q = 0; q < 16; ++q)
      p = fmaf(a_s[wave][fb + q], W2s[(fb + q) * 17 + j], p);
    p += __shfl_xor(p, 16, 64);
    p += __shfl_xor(p, 32, 64);
    if (valid && lane < 16) t[(size_t)v * 16 + j] = dv * p;  // dinv folded
    __threadfence_block();  // order a_s reuse across grid-stride iterations
  }
}

// 16 lanes per node, float4 gathers: sub=lane&15, e=sub>>2, c=sub&3.
// One wave-load covers 16 edges (4 nodes x 4 edges). Row n of t is zeros.
__global__ __launch_bounds__(256) void agg2_kernel(const float4* __restrict__ t4,
                                                   const float* __restrict__ dinv,
                                                   const int* __restrict__ row_start,
                                                   const int* __restrict__ csr,
                                                   const float* __restrict__ b2,
                                                   float* __restrict__ out, int n) {
  int idx = blockIdx.x * 256 + threadIdx.x;
  int v = idx >> 4;
  if (v >= n) return;
  int sub = threadIdx.x & 15;
  int e = sub >> 2, c = sub & 3;
  float dv = dinv[v];
  int e0 = row_start[v], e1 = row_start[v + 1];
  float4 A0 = make_float4(0.f, 0.f, 0.f, 0.f), A1 = A0;
  {
    int s = (e == 0) ? v : n;
    float4 g = t4[(size_t)s * 4 + c];
    A0.x += g.x; A0.y += g.y; A0.z += g.z; A0.w += g.w;
  }
  int i = e0;
  while (i + 4 < e1) {
    int i1 = i + 4 + e;
    int s0 = csr[i + e];
    int s1v = csr[i1];
    int s1 = (i1 < e1) ? s1v : n;
    float4 g0 = t4[(size_t)s0 * 4 + c];
    float4 g1 = t4[(size_t)s1 * 4 + c];
    A0.x += g0.x; A0.y += g0.y; A0.z += g0.z; A0.w += g0.w;
    A1.x += g1.x; A1.y += g1.y; A1.z += g1.z; A1.w += g1.w;
    i += 8;
  }
  if (i < e1) {
    int i0 = i + e;
    int sv = csr[i0];
    int s = (i0 < e1) ? sv : n;
    float4 g = t4[(size_t)s * 4 + c];
    A0.x += g.x; A0.y += g.y; A0.z += g.z; A0.w += g.w;
  }
  A0.x += A1.x; A0.y += A1.y; A0.z += A1.z; A0.w += A1.w;
#pragma unroll
  for (int m = 4; m <= 8; m <<= 1) {  // reduce across e-groups
    A0.x += __shfl_xor(A0.x, m, 64);
    A0.y += __shfl_xor(A0.y, m, 64);
    A0.z += __shfl_xor(A0.z, m, 64);
    A0.w += __shfl_xor(A0.w, m, 64);
  }
  float4 bb = ((const float4*)b2)[c];
  float4 z;
  z.x = fmaf(dv, A0.x, bb.x); z.y = fmaf(dv, A0.y, bb.y);
  z.z = fmaf(dv, A0.z, bb.z); z.w = fmaf(dv, A0.w, bb.w);
  float m1 = fmaxf(fmaxf(z.x, z.y), fmaxf(z.z, z.w));
  m1 = fmaxf(m1, __shfl_xor(m1, 1, 64));  // across c-groups
  m1 = fmaxf(m1, __shfl_xor(m1, 2, 64));
  float4 p;
  p.x = expf(z.x - m1); p.y = expf(z.y - m1);
  p.z = expf(z.z - m1); p.w = expf(z.w - m1);
  float s4 = (p.x + p.y) + (p.z + p.w);
  s4 += __shfl_xor(s4, 1, 64);
  s4 += __shfl_xor(s4, 2, 64);
  float lg = m1 + logf(s4);
  if (e == 0) {
    float4 r;
    r.x = z.x - lg; r.y = z.y - lg; r.z = z.z - lg; r.w = z.w - lg;
    ((float4*)out)[(size_t)v * 4 + c] = r;
  }
}

extern "C" void kernel_launch(void* const* d_in, const int* in_sizes, int n_in,
                              void* d_out, int out_size, void* d_ws, size_t ws_size,
                              hipStream_t stream) {
  const float* x = (const float*)d_in[0];
  const int* edge_index = (const int*)d_in[1];
  const float* W1 = (const float*)d_in[2];
  const float* b1 = (const float*)d_in[3];
  const float* W2 = (const float*)d_in[4];
  const float* b2 = (const float*)d_in[5];
  float* out = (float*)d_out;

  int N_ = in_sizes[0] / 128;
  int E_ = in_sizes[1] / 2;
  const int* src = edge_index;
  const int* dst = edge_index + E_;
  int NBc = (N_ + BMASK) >> BSHIFT;  // 196 buckets of 512 nodes (<= 256)

  char* ws = (char*)d_ws;
  size_t off = 0;
  auto take = [&](size_t bytes) {
    void* p = ws + off;
    off += (bytes + 255) & ~(size_t)255;
    return p;
  };
  unsigned* h1s = (unsigned*)take(((size_t)N_ + 1) * 32 * 4);  // +1 zero row
  // t ((N+1)*16*4) aliases tmp (NBc*CAP*4): tmp dead before agg1 writes t.
  size_t t_bytes = ((size_t)N_ + 1) * 16 * 4, tmp_bytes = (size_t)NBc * CAP * 4;
  void* t_union = take(t_bytes > tmp_bytes ? t_bytes : tmp_bytes);
  float* t = (float*)t_union;
  int* tmp = (int*)t_union;
  float* dinv = (float*)take((size_t)N_ * 4);
  int* cnt = (int*)take((size_t)N_ * 4);
  int* row_start = (int*)take(((size_t)N_ + 1) * 4);
  int* csr = (int*)take(((size_t)E_ + 8) * 4);  // +8 pad for vector tail reads
  int* gbcursor = (int*)take((size_t)NBc * 4);
  int* bsum = (int*)take(512 * 4);
  int* boffs = (int*)take(512 * 4);
  (void)ws_size;

  int nbN = (N_ + 255) / 256;  // 391 (<= 512 for scan2)

  binit_kernel<<<(NBc + 255) / 256, 256, 0, stream>>>(gbcursor, NBc, h1s, N_);
  scatterA_kernel<<<(E_ + CHUNK - 1) / CHUNK, 256, 0, stream>>>(src, dst, E_, NBc,
                                                                gbcursor, tmp);
  hist2_kernel<<<NBc, 256, 0, stream>>>(tmp, gbcursor, N_, cnt);
  dinv_kernel<<<nbN, 256, 0, stream>>>(cnt, dinv, N_);
  scan1_kernel<<<nbN, 256, 0, stream>>>(cnt, N_, row_start, bsum);
  scan2_kernel<<<1, 512, 0, stream>>>(bsum, nbN, boffs);
  scan3_kernel<<<nbN, 256, 0, stream>>>(boffs, N_, E_, row_start);
  scatterB_kernel<<<NBc, 256, 0, stream>>>(tmp, gbcursor, row_start, N_, csr);
  gemm1_kernel<<<(N_ + 127) / 128, 256, 0, stream>>>(x, W1, dinv, h1s, N_);
  agg1_kernel<<<2048, 256, 0, stream>>>((const uint4*)h1s, dinv, row_start, csr,
                                        b1, W2, t, N_);
  agg2_kernel<<<(N_ * 16 + 255) / 256, 256, 0, stream>>>((const float4*)t, dinv,
                                                         row_start, csr, b2, out, N_);
}